// Round 4
// baseline (50.916 us; speedup 1.0000x reference)
//
#include <hip/hip_runtime.h>

#define BB 4
#define SS 4096
#define EE 128
#define KDD 64

// ---------------------------------------------------------------------------
// K1: blocks [0,64): xpart[b][i][c] = sum of x[b, 64+i*252 .. 64+(i+1)*252, c]
//     (16 partial chunks per batch, fixed order -> deterministic)
//     blocks [64,76): idx=bx-64, b=idx/3, role=idx%3 on x[b,0:64] (64x64 GEMM):
//       role 0: value64[b][t][0:64]   = x64 @ Wv[0:64]^T
//       role 1: value64[b][t][64:128] = x64 @ Wv[64:128]^T
//       role 2: key64T[b][k][t] = (t<=k) ? x64[t].Wk[k] : 0
// ---------------------------------------------------------------------------
__global__ __launch_bounds__(256, 2)
void prep(const float* __restrict__ x, const float* __restrict__ Wk,
          const float* __restrict__ Wv,
          float* __restrict__ value64, float* __restrict__ key64T,
          float* __restrict__ xpart)
{
    __shared__ float xs[64][132];
    __shared__ float wst[128][68];
    __shared__ float xred[2][128];
    const int tid = threadIdx.x;
    const int bx = blockIdx.x;

    if (bx < 64) {
        const int b = bx >> 4, i = bx & 15;
        const size_t base = ((size_t)b * SS + 64 + (size_t)i * 252) * EE;
        const int col = tid & 127, rg = tid >> 7;
        float s = 0.f;
        #pragma unroll 7
        for (int r = rg; r < 252; r += 2)
            s += x[base + (size_t)r * EE + col];
        xred[rg][col] = s;
        __syncthreads();
        if (tid < 128)
            xpart[((size_t)b * 16 + i) * 128 + tid] = xred[0][tid] + xred[1][tid];
        return;
    }

    // ---------------- special path: 64x64 tiles on x[b,0:64] ----------------
    const int idx = bx - 64;
    const int b = idx / 3, role = idx % 3;
    const size_t xrow0 = (size_t)b * SS;
    const float* Wbase = (role == 0) ? Wv : (role == 1) ? (Wv + 64 * EE) : Wk;

    #pragma unroll
    for (int i = 0; i < 8; ++i) {
        int f4 = tid + i * 256;
        int row = f4 >> 5, kq = f4 & 31;
        float4 v = *reinterpret_cast<const float4*>(x + (xrow0 + row) * EE + 4 * kq);
        *reinterpret_cast<float4*>(&xs[row][4 * kq]) = v;
    }
    #pragma unroll
    for (int i = 0; i < 8; ++i) {
        int f4 = tid + i * 256;
        int c = f4 & 63, kq = f4 >> 6;
        float4 v = *reinterpret_cast<const float4*>(Wbase + (size_t)c * EE + 4 * kq);
        wst[4 * kq + 0][c] = v.x;
        wst[4 * kq + 1][c] = v.y;
        wst[4 * kq + 2][c] = v.z;
        wst[4 * kq + 3][c] = v.w;
    }
    __syncthreads();

    const int ct = tid & 15, rt = tid >> 4;
    const int c0 = 4 * ct, r0 = 4 * rt;
    float acc[4][4] = {};
    #pragma unroll 4
    for (int k0 = 0; k0 < 128; k0 += 4) {
        float4 a[4], bq[4];
        #pragma unroll
        for (int i = 0; i < 4; ++i) a[i] = *reinterpret_cast<const float4*>(&xs[r0 + i][k0]);
        #pragma unroll
        for (int kk = 0; kk < 4; ++kk) bq[kk] = *reinterpret_cast<const float4*>(&wst[k0 + kk][c0]);
        #pragma unroll
        for (int i = 0; i < 4; ++i) {
            const float4 ai = a[i];
            acc[i][0] = fmaf(ai.x, bq[0].x, acc[i][0]);
            acc[i][1] = fmaf(ai.x, bq[0].y, acc[i][1]);
            acc[i][2] = fmaf(ai.x, bq[0].z, acc[i][2]);
            acc[i][3] = fmaf(ai.x, bq[0].w, acc[i][3]);
            acc[i][0] = fmaf(ai.y, bq[1].x, acc[i][0]);
            acc[i][1] = fmaf(ai.y, bq[1].y, acc[i][1]);
            acc[i][2] = fmaf(ai.y, bq[1].z, acc[i][2]);
            acc[i][3] = fmaf(ai.y, bq[1].w, acc[i][3]);
            acc[i][0] = fmaf(ai.z, bq[2].x, acc[i][0]);
            acc[i][1] = fmaf(ai.z, bq[2].y, acc[i][1]);
            acc[i][2] = fmaf(ai.z, bq[2].z, acc[i][2]);
            acc[i][3] = fmaf(ai.z, bq[2].w, acc[i][3]);
            acc[i][0] = fmaf(ai.w, bq[3].x, acc[i][0]);
            acc[i][1] = fmaf(ai.w, bq[3].y, acc[i][1]);
            acc[i][2] = fmaf(ai.w, bq[3].z, acc[i][2]);
            acc[i][3] = fmaf(ai.w, bq[3].w, acc[i][3]);
        }
    }

    if (role <= 1) {
        const int voff = role * 64 + c0;
        #pragma unroll
        for (int i = 0; i < 4; ++i) {
            float4 o = make_float4(acc[i][0], acc[i][1], acc[i][2], acc[i][3]);
            *reinterpret_cast<float4*>(value64 + ((size_t)b * 64 + r0 + i) * EE + voff) = o;
        }
    } else {
        #pragma unroll
        for (int i = 0; i < 4; ++i)
            #pragma unroll
            for (int j = 0; j < 4; ++j) {
                const int t = r0 + i, k = c0 + j;
                key64T[((size_t)b * 64 + k) * 64 + t] = (t <= k) ? acc[i][j] : 0.f;
            }
    }
}

// ---------------------------------------------------------------------------
// K2: per block (32 q-rows, batch b): inline query GEMM (x,WqT in LDS),
// vsum from 16 partials + Wv, K/V reg-staged (T14) into phase-B LDS, then
// QK (readlane broadcasts) + softmax incl. 4032 zero cols + PV.
// LDS phase-overlaid: A = {xs, wst}; B = {qs, Ks, Vl}; xsum/vs dedicated.
// ---------------------------------------------------------------------------
__device__ __forceinline__ float wave_max64(float v) {
    #pragma unroll
    for (int o = 32; o; o >>= 1) v = fmaxf(v, __shfl_xor(v, o));
    return v;
}
__device__ __forceinline__ float wave_sum64(float v) {
    #pragma unroll
    for (int o = 32; o; o >>= 1) v += __shfl_xor(v, o);
    return v;
}
__device__ __forceinline__ float lanebcast(float v, int l) {
    return __int_as_float(__builtin_amdgcn_readlane(__float_as_int(v), l));
}

__global__ __launch_bounds__(256, 2)
void attn_fused(const float* __restrict__ x, const float* __restrict__ Wq,
                const float* __restrict__ Wv,
                const float* __restrict__ value64, const float* __restrict__ key64T,
                const float* __restrict__ xpart, float* __restrict__ out)
{
    __shared__ __align__(16) char smem[58880];
    float (*xs)[132] = reinterpret_cast<float (*)[132]>(smem);            // A: 16.9 KB
    float (*wst)[68] = reinterpret_cast<float (*)[68]>(smem + 17408);     // A: 34.8 KB
    float* qs    = reinterpret_cast<float*>(smem);                        // B: [32*64]
    float* Ks    = reinterpret_cast<float*>(smem + 8192);                 // B: [64*64]
    float* Vl    = reinterpret_cast<float*>(smem + 24576);                // B: [64*128]
    float* xsumS = reinterpret_cast<float*>(smem + 57344);                // [128]
    float* vsS   = reinterpret_cast<float*>(smem + 57856);                // [128]

    const int tid = threadIdx.x;
    const int b = blockIdx.y;
    const int s0 = blockIdx.x * 32;

    // ---- phase A staging: x tile 32x128 + WqT ----
    #pragma unroll
    for (int i = 0; i < 4; ++i) {
        int f4 = tid + i * 256;
        int row = f4 >> 5, kq = f4 & 31;
        float4 v = *reinterpret_cast<const float4*>(x + ((size_t)b * SS + s0 + row) * EE + 4 * kq);
        *reinterpret_cast<float4*>(&xs[row][4 * kq]) = v;
    }
    #pragma unroll
    for (int i = 0; i < 8; ++i) {
        int f4 = tid + i * 256;
        int c = f4 & 63, kq = f4 >> 6;
        float4 v = *reinterpret_cast<const float4*>(Wq + (size_t)c * EE + 4 * kq);
        wst[4 * kq + 0][c] = v.x;
        wst[4 * kq + 1][c] = v.y;
        wst[4 * kq + 2][c] = v.z;
        wst[4 * kq + 3][c] = v.w;
    }
    // ---- T14 reg-stage K/V (latency hides under the GEMM) ----
    float4 kreg[4], vreg[8];
    #pragma unroll
    for (int i = 0; i < 4; ++i)
        kreg[i] = *reinterpret_cast<const float4*>(key64T + (size_t)b * 4096 + 4 * (tid + i * 256));
    #pragma unroll
    for (int i = 0; i < 8; ++i)
        vreg[i] = *reinterpret_cast<const float4*>(value64 + (size_t)b * 8192 + 4 * (tid + i * 256));
    // ---- xsum from 16 fixed-order partials ----
    if (tid < 128) {
        float s = 0.f;
        #pragma unroll
        for (int i = 0; i < 16; ++i)
            s += xpart[((size_t)b * 16 + i) * 128 + tid];
        xsumS[tid] = s;             // dedicated region, never aliased
    }
    __syncthreads();                // A data + xsum visible

    // ---- query GEMM: 32x64, thread tile 2x4 ----
    const int ct = tid & 15, rt = tid >> 4;
    const int c0 = 4 * ct, r0 = 2 * rt;
    float acc[2][4] = {};
    #pragma unroll 4
    for (int k0 = 0; k0 < 128; k0 += 4) {
        float4 a[2], bq[4];
        #pragma unroll
        for (int i = 0; i < 2; ++i) a[i] = *reinterpret_cast<const float4*>(&xs[r0 + i][k0]);
        #pragma unroll
        for (int kk = 0; kk < 4; ++kk) bq[kk] = *reinterpret_cast<const float4*>(&wst[k0 + kk][c0]);
        #pragma unroll
        for (int i = 0; i < 2; ++i) {
            const float4 ai = a[i];
            acc[i][0] = fmaf(ai.x, bq[0].x, acc[i][0]);
            acc[i][1] = fmaf(ai.x, bq[0].y, acc[i][1]);
            acc[i][2] = fmaf(ai.x, bq[0].z, acc[i][2]);
            acc[i][3] = fmaf(ai.x, bq[0].w, acc[i][3]);
            acc[i][0] = fmaf(ai.y, bq[1].x, acc[i][0]);
            acc[i][1] = fmaf(ai.y, bq[1].y, acc[i][1]);
            acc[i][2] = fmaf(ai.y, bq[1].z, acc[i][2]);
            acc[i][3] = fmaf(ai.y, bq[1].w, acc[i][3]);
            acc[i][0] = fmaf(ai.z, bq[2].x, acc[i][0]);
            acc[i][1] = fmaf(ai.z, bq[2].y, acc[i][1]);
            acc[i][2] = fmaf(ai.z, bq[2].z, acc[i][2]);
            acc[i][3] = fmaf(ai.z, bq[2].w, acc[i][3]);
            acc[i][0] = fmaf(ai.w, bq[3].x, acc[i][0]);
            acc[i][1] = fmaf(ai.w, bq[3].y, acc[i][1]);
            acc[i][2] = fmaf(ai.w, bq[3].z, acc[i][2]);
            acc[i][3] = fmaf(ai.w, bq[3].w, acc[i][3]);
        }
    }
    __syncthreads();                // GEMM done: phase-A LDS dead

    // ---- phase B fill: qs from acc, Ks/Vl from regs, vs from xsum.Wv ----
    *reinterpret_cast<float4*>(&qs[(r0 + 0) * 64 + c0]) =
        make_float4(acc[0][0], acc[0][1], acc[0][2], acc[0][3]);
    *reinterpret_cast<float4*>(&qs[(r0 + 1) * 64 + c0]) =
        make_float4(acc[1][0], acc[1][1], acc[1][2], acc[1][3]);
    #pragma unroll
    for (int i = 0; i < 4; ++i)
        *reinterpret_cast<float4*>(&Ks[4 * (tid + i * 256)]) = kreg[i];
    #pragma unroll
    for (int i = 0; i < 8; ++i)
        *reinterpret_cast<float4*>(&Vl[4 * (tid + i * 256)]) = vreg[i];
    if (tid < 128) {
        float a = 0.f;
        #pragma unroll 8
        for (int e = 0; e < 128; e += 4) {
            float4 w = *reinterpret_cast<const float4*>(Wv + (size_t)tid * EE + e);
            a = fmaf(xsumS[e + 0], w.x, a);
            a = fmaf(xsumS[e + 1], w.y, a);
            a = fmaf(xsumS[e + 2], w.z, a);
            a = fmaf(xsumS[e + 3], w.w, a);
        }
        vsS[tid] = a;
    }
    __syncthreads();                // qs, Ks, Vl, vs visible

    // ---- QK + softmax + PV: 4 waves x 8 rows ----
    const int wave = tid >> 6, lane = tid & 63;
    const int rbase = wave * 8;

    float q[8], a[8];
    #pragma unroll
    for (int r = 0; r < 8; ++r) {
        q[r] = qs[(rbase + r) * 64 + lane];
        a[r] = 0.f;
    }
    #pragma unroll
    for (int k = 0; k < 64; ++k) {
        float kv = Ks[k * 64 + lane];         // zero above diagonal
        #pragma unroll
        for (int r = 0; r < 8; ++r)
            a[r] = fmaf(lanebcast(q[r], k), kv, a[r]);
    }
    float w[8], e[8], iz[8];
    #pragma unroll
    for (int r = 0; r < 8; ++r) {
        float m = fmaxf(wave_max64(a[r]), 0.f);
        w[r] = __expf(a[r] - m);
        e[r] = __expf(-m);
        float z = wave_sum64(w[r]) + (float)(SS - 64) * e[r];
        iz[r] = 1.f / z;
    }
    float ox[8] = {}, oy[8] = {};
    #pragma unroll
    for (int t = 0; t < 64; ++t) {
        float2 vv = *reinterpret_cast<const float2*>(&Vl[t * 128 + 2 * lane]);
        #pragma unroll
        for (int r = 0; r < 8; ++r) {
            float wt = lanebcast(w[r], t);
            ox[r] = fmaf(wt, vv.x, ox[r]);
            oy[r] = fmaf(wt, vv.y, oy[r]);
        }
    }
    float2 vsv = *reinterpret_cast<const float2*>(&vsS[2 * lane]);
    #pragma unroll
    for (int r = 0; r < 8; ++r) {
        float2 o;
        o.x = (ox[r] + e[r] * vsv.x) * iz[r];
        o.y = (oy[r] + e[r] * vsv.y) * iz[r];
        *reinterpret_cast<float2*>(out + ((size_t)b * SS + s0 + rbase + r) * EE + 2 * lane) = o;
    }
}

// ---------------------------------------------------------------------------
extern "C" void kernel_launch(void* const* d_in, const int* in_sizes, int n_in,
                              void* d_out, int out_size, void* d_ws, size_t ws_size,
                              hipStream_t stream)
{
    const float* x  = (const float*)d_in[0];
    const float* Wk = (const float*)d_in[1];
    const float* Wq = (const float*)d_in[2];
    const float* Wv = (const float*)d_in[3];
    float* out = (float*)d_out;

    float* ws      = (float*)d_ws;
    float* value64 = ws;                                    // BB*64*EE
    float* key64T  = value64 + (size_t)BB * 64 * EE;        // BB*64*64
    float* xpart   = key64T + (size_t)BB * 64 * 64;         // BB*16*128

    prep<<<76, 256, 0, stream>>>(x, Wk, Wv, value64, key64T, xpart);
    attn_fused<<<dim3(SS / 32, BB), 256, 0, stream>>>(x, Wq, Wv, value64, key64T, xpart, out);
}

// Round 5
// 30.269 us; speedup vs baseline: 1.6821x; 1.6821x over previous
//
#include <hip/hip_runtime.h>

#define BB 4
#define SS 4096
#define EE 128

typedef __attribute__((ext_vector_type(8))) short bf16x8;
typedef __attribute__((ext_vector_type(4))) float f32x4;

__device__ __forceinline__ unsigned short f2bf(float f) {
    unsigned u = __float_as_uint(f);
    u = (u + 0x7FFFu + ((u >> 16) & 1u)) >> 16;
    return (unsigned short)u;
}
__device__ __forceinline__ float bf2f(unsigned short h) {
    return __uint_as_float(((unsigned)h) << 16);
}
__device__ __forceinline__ void split8(const float* p, bf16x8& h, bf16x8& l) {
    float4 v0 = *reinterpret_cast<const float4*>(p);
    float4 v1 = *reinterpret_cast<const float4*>(p + 4);
    float f[8] = {v0.x, v0.y, v0.z, v0.w, v1.x, v1.y, v1.z, v1.w};
    #pragma unroll
    for (int i = 0; i < 8; ++i) {
        unsigned short hb = f2bf(f[i]);
        h[i] = (short)hb;
        l[i] = (short)f2bf(f[i] - bf2f(hb));
    }
}

// ---------------------------------------------------------------------------
// prep1: blocks [0,256): xpart[b][i][c] = sum of x[b, 64+i*63 .. +63, c]
//        blocks [256,268): per (b, role) 64x64 GEMM on x[b,0:64]:
//          role 0/1: Vt[b][v][t] = bf16( x64 @ Wv^T )  (transposed store)
//          role 2:   key64T[b][j][t] = (t<=j) ? x64[t].Wk[j] : 0   (f32)
// ---------------------------------------------------------------------------
__global__ __launch_bounds__(256, 2)
void prep1(const float* __restrict__ x, const float* __restrict__ Wk,
           const float* __restrict__ Wv,
           unsigned short* __restrict__ Vt, float* __restrict__ key64T,
           float* __restrict__ xpart)
{
    __shared__ float xs[64][132];
    __shared__ float wst[128][68];
    const int tid = threadIdx.x;
    const int bx = blockIdx.x;

    if (bx < 256) {
        __shared__ float xred[2][128];
        const int b = bx >> 6, i = bx & 63;
        const size_t base = ((size_t)b * SS + 64 + (size_t)i * 63) * EE;
        const int col = tid & 127, rg = tid >> 7;
        float s = 0.f;
        for (int r = rg; r < 63; r += 2)
            s += x[base + (size_t)r * EE + col];
        xred[rg][col] = s;
        __syncthreads();
        if (tid < 128)
            xpart[((size_t)b * 64 + i) * 128 + tid] = xred[0][tid] + xred[1][tid];
        return;
    }

    const int idx = bx - 256;
    const int b = idx / 3, role = idx % 3;
    const size_t xrow0 = (size_t)b * SS;
    const float* Wbase = (role == 0) ? Wv : (role == 1) ? (Wv + 64 * EE) : Wk;

    #pragma unroll
    for (int i = 0; i < 8; ++i) {
        int f4 = tid + i * 256;
        int row = f4 >> 5, kq = f4 & 31;
        float4 v = *reinterpret_cast<const float4*>(x + (xrow0 + row) * EE + 4 * kq);
        *reinterpret_cast<float4*>(&xs[row][4 * kq]) = v;
    }
    #pragma unroll
    for (int i = 0; i < 8; ++i) {
        int f4 = tid + i * 256;
        int c = f4 & 63, kq = f4 >> 6;
        float4 v = *reinterpret_cast<const float4*>(Wbase + (size_t)c * EE + 4 * kq);
        wst[4 * kq + 0][c] = v.x;
        wst[4 * kq + 1][c] = v.y;
        wst[4 * kq + 2][c] = v.z;
        wst[4 * kq + 3][c] = v.w;
    }
    __syncthreads();

    const int ct = tid & 15, rt = tid >> 4;
    const int c0 = 4 * ct, r0 = 4 * rt;
    float acc[4][4] = {};
    #pragma unroll 4
    for (int k0 = 0; k0 < 128; k0 += 4) {
        float4 a[4], bq[4];
        #pragma unroll
        for (int i = 0; i < 4; ++i) a[i] = *reinterpret_cast<const float4*>(&xs[r0 + i][k0]);
        #pragma unroll
        for (int kk = 0; kk < 4; ++kk) bq[kk] = *reinterpret_cast<const float4*>(&wst[k0 + kk][c0]);
        #pragma unroll
        for (int i = 0; i < 4; ++i) {
            const float4 ai = a[i];
            acc[i][0] = fmaf(ai.x, bq[0].x, acc[i][0]);
            acc[i][1] = fmaf(ai.x, bq[0].y, acc[i][1]);
            acc[i][2] = fmaf(ai.x, bq[0].z, acc[i][2]);
            acc[i][3] = fmaf(ai.x, bq[0].w, acc[i][3]);
            acc[i][0] = fmaf(ai.y, bq[1].x, acc[i][0]);
            acc[i][1] = fmaf(ai.y, bq[1].y, acc[i][1]);
            acc[i][2] = fmaf(ai.y, bq[1].z, acc[i][2]);
            acc[i][3] = fmaf(ai.y, bq[1].w, acc[i][3]);
            acc[i][0] = fmaf(ai.z, bq[2].x, acc[i][0]);
            acc[i][1] = fmaf(ai.z, bq[2].y, acc[i][1]);
            acc[i][2] = fmaf(ai.z, bq[2].z, acc[i][2]);
            acc[i][3] = fmaf(ai.z, bq[2].w, acc[i][3]);
            acc[i][0] = fmaf(ai.w, bq[3].x, acc[i][0]);
            acc[i][1] = fmaf(ai.w, bq[3].y, acc[i][1]);
            acc[i][2] = fmaf(ai.w, bq[3].z, acc[i][2]);
            acc[i][3] = fmaf(ai.w, bq[3].w, acc[i][3]);
        }
    }

    if (role <= 1) {
        const int voff = role * 64;
        #pragma unroll
        for (int j = 0; j < 4; ++j) {
            ushort4 pk = make_ushort4(f2bf(acc[0][j]), f2bf(acc[1][j]),
                                      f2bf(acc[2][j]), f2bf(acc[3][j]));
            *reinterpret_cast<ushort4*>(Vt + (size_t)b * 8192 + (size_t)(voff + c0 + j) * 64 + r0) = pk;
        }
    } else {
        #pragma unroll
        for (int i = 0; i < 4; ++i)
            #pragma unroll
            for (int j = 0; j < 4; ++j) {
                const int t = r0 + i, k = c0 + j;
                key64T[((size_t)b * 64 + k) * 64 + t] = (t <= k) ? acc[i][j] : 0.f;
            }
    }
}

// ---------------------------------------------------------------------------
// prep2: blocks [0,16): b=bx>>2, k-quarter kq=bx&3:
//   Mt[b][t][k] = sum_j Wq[j][k] * key64T[b][j][t]  -> bf16 hi/lo (transposed)
//        blocks [16,20): vsum[b] = (sum_i xpart[b][i]) @ Wv^T   (f32)
// ---------------------------------------------------------------------------
__global__ __launch_bounds__(256)
void prep2(const float* __restrict__ Wq, const float* __restrict__ Wv,
           const float* __restrict__ key64T, const float* __restrict__ xpart,
           unsigned short* __restrict__ Mth, unsigned short* __restrict__ Mtl,
           float* __restrict__ vsum)
{
    const int tid = threadIdx.x, bx = blockIdx.x;
    if (bx < 16) {
        __shared__ float ks[64][66];
        __shared__ float wqs[64][36];
        const int b = bx >> 2, kq = bx & 3;
        #pragma unroll
        for (int i = 0; i < 4; ++i) {
            int f4 = tid + i * 256;
            int j = f4 >> 4, t4 = f4 & 15;
            float4 v = *reinterpret_cast<const float4*>(key64T + (size_t)b * 4096 + (size_t)j * 64 + 4 * t4);
            *reinterpret_cast<float4*>(&ks[j][4 * t4]) = v;
        }
        #pragma unroll
        for (int i = 0; i < 2; ++i) {
            int f4 = tid + i * 256;
            int j = f4 >> 3, kk = f4 & 7;
            float4 v = *reinterpret_cast<const float4*>(Wq + (size_t)j * EE + kq * 32 + 4 * kk);
            *reinterpret_cast<float4*>(&wqs[j][4 * kk]) = v;
        }
        __syncthreads();
        const int t0 = (tid >> 3) * 2, k0 = (tid & 7) * 4;
        float acc[2][4] = {};
        #pragma unroll
        for (int j = 0; j < 64; ++j) {
            float4 w4 = *reinterpret_cast<const float4*>(&wqs[j][k0]);
            float kv0 = ks[j][t0], kv1 = ks[j][t0 + 1];
            acc[0][0] = fmaf(kv0, w4.x, acc[0][0]);
            acc[0][1] = fmaf(kv0, w4.y, acc[0][1]);
            acc[0][2] = fmaf(kv0, w4.z, acc[0][2]);
            acc[0][3] = fmaf(kv0, w4.w, acc[0][3]);
            acc[1][0] = fmaf(kv1, w4.x, acc[1][0]);
            acc[1][1] = fmaf(kv1, w4.y, acc[1][1]);
            acc[1][2] = fmaf(kv1, w4.z, acc[1][2]);
            acc[1][3] = fmaf(kv1, w4.w, acc[1][3]);
        }
        #pragma unroll
        for (int dt = 0; dt < 2; ++dt) {
            unsigned short h0 = f2bf(acc[dt][0]), h1 = f2bf(acc[dt][1]);
            unsigned short h2 = f2bf(acc[dt][2]), h3 = f2bf(acc[dt][3]);
            ushort4 hv = make_ushort4(h0, h1, h2, h3);
            ushort4 lv = make_ushort4(f2bf(acc[dt][0] - bf2f(h0)),
                                      f2bf(acc[dt][1] - bf2f(h1)),
                                      f2bf(acc[dt][2] - bf2f(h2)),
                                      f2bf(acc[dt][3] - bf2f(h3)));
            const size_t off = (size_t)b * 8192 + (size_t)(t0 + dt) * 128 + kq * 32 + k0;
            *reinterpret_cast<ushort4*>(Mth + off) = hv;
            *reinterpret_cast<ushort4*>(Mtl + off) = lv;
        }
    } else {
        __shared__ float xsum[128];
        const int b = bx - 16;
        if (tid < 128) {
            float s = 0.f;
            #pragma unroll 8
            for (int i = 0; i < 64; ++i) s += xpart[((size_t)b * 64 + i) * 128 + tid];
            xsum[tid] = s;
        }
        __syncthreads();
        if (tid < 128) {
            float a = 0.f;
            #pragma unroll 8
            for (int e = 0; e < 128; e += 4) {
                float4 w = *reinterpret_cast<const float4*>(Wv + (size_t)tid * EE + e);
                a = fmaf(xsum[e + 0], w.x, a);
                a = fmaf(xsum[e + 1], w.y, a);
                a = fmaf(xsum[e + 2], w.z, a);
                a = fmaf(xsum[e + 3], w.w, a);
            }
            vsum[(size_t)b * EE + tid] = a;
        }
    }
}

// ---------------------------------------------------------------------------
// main: 1 wave per block, 16 q-rows. S = x@M via split-bf16 MFMA (3x),
// in-register softmax (+ 4032 zero-col term), P relayout via 4KB LDS,
// out = P@V (bf16 MFMA) + e*vsum, normalized. No __syncthreads at all.
// ---------------------------------------------------------------------------
__global__ __launch_bounds__(64)
void attn_main(const float* __restrict__ x, const short* __restrict__ Mth,
               const short* __restrict__ Mtl, const short* __restrict__ Vt,
               const float* __restrict__ vsum, float* __restrict__ out)
{
    __shared__ float Plds[16][68];
    const int l = threadIdx.x;
    const int b = blockIdx.y;
    const int s0 = blockIdx.x * 16;
    const int lm = l & 15, lg = l >> 4;

    // ---- x A-frags (hi/lo split) ----
    bf16x8 xh[4], xl[4];
    const float* xrow = x + ((size_t)b * SS + s0 + lm) * EE + lg * 8;
    #pragma unroll
    for (int kt = 0; kt < 4; ++kt)
        split8(xrow + kt * 32, xh[kt], xl[kt]);

    // ---- S = x @ M : 4 col-tiles x (4 k-tiles x 3 split-mfma) ----
    f32x4 sa[4];
    const short* mh_base = Mth + (size_t)b * 8192 + lg * 8;
    const short* ml_base = Mtl + (size_t)b * 8192 + lg * 8;
    #pragma unroll
    for (int ct = 0; ct < 4; ++ct) {
        f32x4 a = {0.f, 0.f, 0.f, 0.f};
        const size_t trow = (size_t)(ct * 16 + lm) * 128;
        #pragma unroll
        for (int kt = 0; kt < 4; ++kt) {
            bf16x8 mh = *reinterpret_cast<const bf16x8*>(mh_base + trow + kt * 32);
            bf16x8 ml = *reinterpret_cast<const bf16x8*>(ml_base + trow + kt * 32);
            a = __builtin_amdgcn_mfma_f32_16x16x32_bf16(xh[kt], mh, a, 0, 0, 0);
            a = __builtin_amdgcn_mfma_f32_16x16x32_bf16(xl[kt], mh, a, 0, 0, 0);
            a = __builtin_amdgcn_mfma_f32_16x16x32_bf16(xh[kt], ml, a, 0, 0, 0);
        }
        sa[ct] = a;
    }

    // ---- softmax over 4096 cols (64 real + 4032 exact zeros) ----
    // C/D layout: row = lg*4 + r, col = ct*16 + lm  (rows owned per lane-group)
    float e[4], iz[4];
    #pragma unroll
    for (int r = 0; r < 4; ++r) {
        float m = fmaxf(fmaxf(sa[0][r], sa[1][r]), fmaxf(sa[2][r], sa[3][r]));
        #pragma unroll
        for (int o = 1; o < 16; o <<= 1) m = fmaxf(m, __shfl_xor(m, o));
        m = fmaxf(m, 0.f);
        float w0 = __expf(sa[0][r] - m), w1 = __expf(sa[1][r] - m);
        float w2 = __expf(sa[2][r] - m), w3 = __expf(sa[3][r] - m);
        sa[0][r] = w0; sa[1][r] = w1; sa[2][r] = w2; sa[3][r] = w3;
        float z = (w0 + w1) + (w2 + w3);
        #pragma unroll
        for (int o = 1; o < 16; o <<= 1) z += __shfl_xor(z, o);
        e[r] = __expf(-m);
        z += 4032.f * e[r];
        iz[r] = 1.f / z;
    }

    // ---- P relayout: C/D layout -> A-frag layout via LDS ----
    #pragma unroll
    for (int ct = 0; ct < 4; ++ct)
        #pragma unroll
        for (int r = 0; r < 4; ++r)
            Plds[lg * 4 + r][ct * 16 + lm] = sa[ct][r];
    // same-wave write->read; compiler inserts lgkmcnt wait on the dependence
    bf16x8 pf[2];
    #pragma unroll
    for (int kt2 = 0; kt2 < 2; ++kt2) {
        const float* pr = &Plds[lm][kt2 * 32 + lg * 8];
        #pragma unroll
        for (int i = 0; i < 8; ++i) pf[kt2][i] = (short)f2bf(pr[i]);
    }

    // ---- PV + vsum term + normalize + store ----
    const short* vb = Vt + (size_t)b * 8192 + lg * 8;
    const float* vsb = vsum + (size_t)b * EE;
    const size_t obase = ((size_t)b * SS + s0) * EE;
    #pragma unroll
    for (int ct = 0; ct < 8; ++ct) {
        const int col = ct * 16 + lm;
        bf16x8 v0 = *reinterpret_cast<const bf16x8*>(vb + (size_t)col * 64);
        bf16x8 v1 = *reinterpret_cast<const bf16x8*>(vb + (size_t)col * 64 + 32);
        f32x4 a = {0.f, 0.f, 0.f, 0.f};
        a = __builtin_amdgcn_mfma_f32_16x16x32_bf16(pf[0], v0, a, 0, 0, 0);
        a = __builtin_amdgcn_mfma_f32_16x16x32_bf16(pf[1], v1, a, 0, 0, 0);
        const float vs = vsb[col];
        #pragma unroll
        for (int r = 0; r < 4; ++r)
            out[obase + (size_t)(lg * 4 + r) * EE + col] = (a[r] + e[r] * vs) * iz[r];
    }
}

// ---------------------------------------------------------------------------
extern "C" void kernel_launch(void* const* d_in, const int* in_sizes, int n_in,
                              void* d_out, int out_size, void* d_ws, size_t ws_size,
                              hipStream_t stream)
{
    const float* x  = (const float*)d_in[0];
    const float* Wk = (const float*)d_in[1];
    const float* Wq = (const float*)d_in[2];
    const float* Wv = (const float*)d_in[3];
    float* out = (float*)d_out;

    float* ws = (float*)d_ws;
    float* key64T = ws;                       // 4*64*64   = 16384 f32
    float* xpart  = key64T + 16384;           // 4*64*128  = 32768 f32
    float* vsum   = xpart + 32768;            // 4*128     = 512 f32
    unsigned short* Mth = (unsigned short*)(vsum + 512);   // 4*64*128 bf16
    unsigned short* Mtl = Mth + 32768;                     // 4*64*128 bf16
    unsigned short* Vt  = Mtl + 32768;                     // 4*128*64 bf16

    prep1<<<268, 256, 0, stream>>>(x, Wk, Wv, Vt, key64T, xpart);
    prep2<<<20, 256, 0, stream>>>(Wq, Wv, key64T, xpart, Mth, Mtl, vsum);
    attn_main<<<dim3(SS / 16, BB), 64, 0, stream>>>(
        x, (const short*)Mth, (const short*)Mtl, (const short*)Vt, vsum, out);
}